// Round 11
// baseline (250.649 us; speedup 1.0000x reference)
//
#include <hip/hip_runtime.h>
#include <hip/hip_fp16.h>

// ---------------------------------------------------------------------------
// 2-layer GCN on MI355X.
//   GCNConv(x) = A_hat (x W) + b = (A_hat x) W + b, and emb[labels]@W1 =
//   (emb@W1)[labels]. Layer 1 gathers from a 1000-row table -> put it in LDS.
// CSR build (zero global atomics): K1 hist / K2 colscan / K2b ebase /
// K3 scatter / K4 bsort (+dinv fold) / scale (csr.y *= dinv[src]).
// agg1: persistent 256 blocks x 512 thr; 2 feature passes; per pass stage a
// 64-feature fp16 slab (1000 x 72-half rows = 141KB, padded stride for bank
// spread) in LDS; 8 edges per wave-instr (8 groups x 8 lanes, group-uniform
// record loads, ds_read_b128 of slab) -> issue-bound, no gather latency.
// agg2: R8 pair-gather shape (beyond-L2-BW bound ~3TB/s; structure-invariant).
// ---------------------------------------------------------------------------

#define CHUNKS 256  // chunk = ceil(e/256) = 6250 for e=1.6M
#define BSTAGE 2816 // bucket stage entries (avg bucket = 2048)
#define SLABSTRIDE 72  // halves per slab row (64 data + 8 pad) -> 144B

// K1: per-chunk histogram of dst-buckets (nb = ceil(n/64) <= 1024).
__global__ __launch_bounds__(1024) void hist_kernel(const int* __restrict__ dst,
                                                    int* __restrict__ hist,
                                                    int e, int chunk, int nb) {
  __shared__ unsigned lh[1024];
  int b = blockIdx.x, t = threadIdx.x;
  lh[t] = 0;
  __syncthreads();
  int start = b * chunk, end = min(e, start + chunk);
  for (int i = start + t; i < end; i += 1024) atomicAdd(&lh[dst[i] >> 6], 1u);
  __syncthreads();
  if (t < nb) hist[(size_t)t * CHUNKS + b] = (int)lh[t];
}

// K2: one wave per bucket k: exclusive scan of hist[k][*] over chunks.
__global__ __launch_bounds__(256) void colscan_kernel(const int* __restrict__ hist,
                                                      int* __restrict__ off,
                                                      int* __restrict__ tot,
                                                      int nb, int bact) {
  int k = (blockIdx.x * 256 + threadIdx.x) >> 6;
  int lane = threadIdx.x & 63;
  if (k >= nb) return;
  int carry = 0;
  for (int r = 0; r < CHUNKS / 64; ++r) {
    int b = r * 64 + lane;
    int h = (b < bact) ? hist[(size_t)k * CHUNKS + b] : 0;
    int x = h;
#pragma unroll
    for (int d = 1; d < 64; d <<= 1) {
      int tt = __shfl_up(x, d, 64);
      if (lane >= d) x += tt;
    }
    if (b < bact) off[(size_t)k * CHUNKS + b] = carry + x - h;
    carry += __shfl(x, 63, 64);
  }
  if (lane == 0) tot[k] = carry;
}

// K2b: single block: exclusive scan of tot[nb] -> ebase[nb+1].
__global__ __launch_bounds__(1024) void ebase_kernel(const int* __restrict__ tot,
                                                     int* __restrict__ ebase, int nb) {
  __shared__ int wsum[16];
  int t = threadIdx.x, lane = t & 63, wv = t >> 6;
  int v = (t < nb) ? tot[t] : 0;
  int x = v;
#pragma unroll
  for (int d = 1; d < 64; d <<= 1) {
    int tt = __shfl_up(x, d, 64);
    if (lane >= d) x += tt;
  }
  if (lane == 63) wsum[wv] = x;
  __syncthreads();
  int o = 0;
#pragma unroll
  for (int w = 0; w < 16; ++w) o += (w < wv) ? wsum[w] : 0;
  int excl = x - v + o;
  if (t < nb) ebase[t] = excl;
  if (t == nb - 1) ebase[nb] = excl + v;
}

// K3: scatter edges into bucket-grouped records (LDS rank, no global atomics).
__global__ __launch_bounds__(1024) void scatter_kernel(
    const int* __restrict__ src, const int* __restrict__ dst,
    const float* __restrict__ w, const int* __restrict__ labels,
    const int* __restrict__ off, const int* __restrict__ ebase,
    int2* __restrict__ brec, int e, int chunk, int nb) {
  __shared__ unsigned bincnt[1024];
  __shared__ int gbase[1024];
  int b = blockIdx.x, t = threadIdx.x;
  bincnt[t] = 0;
  if (t < nb) gbase[t] = ebase[t] + off[(size_t)t * CHUNKS + b];
  __syncthreads();
  int start = b * chunk, end = min(e, start + chunk);
  int s[7], d[7], lb[7], ps[7];
  float wv[7];
#pragma unroll
  for (int u = 0; u < 7; ++u) {
    int i = start + u * 1024 + t;
    bool ok = i < end;
    s[u] = ok ? src[i] : 0;
    d[u] = ok ? dst[i] : 0;
    wv[u] = ok ? w[i] : 0.f;
  }
#pragma unroll
  for (int u = 0; u < 7; ++u) lb[u] = labels[s[u]];
#pragma unroll
  for (int u = 0; u < 7; ++u) ps[u] = gbase[d[u] >> 6];
#pragma unroll
  for (int u = 0; u < 7; ++u) {
    int i = start + u * 1024 + t;
    if (i < end) {
      int k = d[u] >> 6;
      unsigned lr = atomicAdd(&bincnt[k], 1u);
      unsigned rx = (unsigned)s[u] | ((unsigned)(d[u] & 63) << 16) |
                    ((unsigned)lb[u] << 22);
      brec[ps[u] + (int)lr] = make_int2((int)rx, __float_as_int(wv[u]));
    }
  }
}

// K4: per-bucket 64-bin sort: brec -> csr (src|label<<16, w), + rs[] + dinv.
__global__ __launch_bounds__(256) void bsort_kernel(const int2* __restrict__ brec,
                                                    const int* __restrict__ ebase,
                                                    int2* __restrict__ csr,
                                                    int* __restrict__ rs,
                                                    float* __restrict__ dinv, int n) {
  __shared__ int2 stage[BSTAGE];
  __shared__ unsigned h64[64];
  __shared__ unsigned cur[64];
  __shared__ float rsum[64];
  int k = blockIdx.x, t = threadIdx.x;
  int e0 = ebase[k], e1 = ebase[k + 1], cnt = e1 - e0;
  if (t < 64) { h64[t] = 0; rsum[t] = 0.f; }
  __syncthreads();
  bool fits = (cnt <= BSTAGE);
  for (int i = t; i < cnt; i += 256) {
    int2 r = brec[e0 + i];
    if (fits) stage[i] = r;
    unsigned dl = ((unsigned)r.x >> 16) & 63u;
    atomicAdd(&h64[dl], 1u);
    atomicAdd(&rsum[dl], __int_as_float(r.y));
  }
  __syncthreads();
  if (t < 64) {
    int hv = (int)h64[t];
    int x = hv;
#pragma unroll
    for (int d = 1; d < 64; d <<= 1) {
      int tt = __shfl_up(x, d, 64);
      if (t >= d) x += tt;
    }
    int ex = x - hv;
    cur[t] = (unsigned)(e0 + ex);
    int v = k * 64 + t;
    if (v <= n) rs[v] = e0 + ex;
    if (v < n) dinv[v] = rsqrtf(1.0f + rsum[t]);
  }
  __syncthreads();
  for (int i = t; i < cnt; i += 256) {
    int2 r = fits ? stage[i] : brec[e0 + i];
    unsigned rx = (unsigned)r.x;
    int dl = (int)((rx >> 16) & 63u);
    int pos = (int)atomicAdd(&cur[dl], 1u);
    csr[pos] = make_int2((int)((rx & 0xffffu) | ((rx >> 22) << 16)), r.y);
  }
}

// csr.y *= dinv[src]  (prescale so agg inner loops are pure)
__global__ void scale_kernel(int2* __restrict__ csr, const float* __restrict__ dinv, int e) {
  int i = blockIdx.x * blockDim.x + threadIdx.x;
  if (i < e) {
    int2 c = csr[i];
    c.y = __float_as_int(__int_as_float(c.y) * dinv[c.x & 0xffff]);
    csr[i] = c;
  }
}

// temb = emb_table @ W1, stored PASS-MAJOR fp16: temb2[p][vocab][64], p=col/64
__global__ void temb_kernel(const float* __restrict__ emb, const float* __restrict__ W1,
                            __half* __restrict__ temb2, int vocab) {
  int r = blockIdx.x, j = threadIdx.x;
  __shared__ float xs[128];
  xs[j] = emb[r * 128 + j];
  __syncthreads();
  float acc = 0.f;
#pragma unroll 8
  for (int k = 0; k < 128; ++k) acc = fmaf(xs[k], W1[k * 128 + j], acc);
  int p = j >> 6, c = j & 63;
  temb2[(size_t)p * vocab * 64 + r * 64 + c] = __float2half_rn(acc);
}

// Layer 1: out1 = relu(A_hat temb[labels] + b1), LDS-slab version.
// Persistent: 256 blocks x 512 threads (1/CU; LDS 141KB). Two passes of 64
// features. Inner loop: 8 edges per wave-instr (8 groups x 8 lanes).
__global__ __launch_bounds__(512) void agg1_kernel(
    const int* __restrict__ rs, const int2* __restrict__ csr,
    const float* __restrict__ dinv, const int* __restrict__ labels,
    const __half* __restrict__ temb2, const float* __restrict__ b1,
    __half* __restrict__ out1, int n, int vocab) {
  __shared__ __half slab[1000 * SLABSTRIDE];  // 141KB (vocab=1000)
  int t = threadIdx.x;
  int gw = (blockIdx.x * 512 + t) >> 6;  // global wave id (0..2047)
  int lane = t & 63;
  int g = lane >> 3, li = lane & 7;
  for (int p = 0; p < 2; ++p) {
    __syncthreads();
    // stage slab p: vocab*64 halves = vocab*8 float4, coalesced
    {
      const float4* srcp = (const float4*)(temb2 + (size_t)p * vocab * 64);
      for (int i = t; i < vocab * 8; i += 512) {
        int row = i >> 3, c8 = i & 7;
        *(float4*)&slab[row * SLABSTRIDE + c8 * 8] = srcp[i];
      }
    }
    __syncthreads();
    for (int wid = gw; wid < n; wid += 2048) {
      int r0 = rs[wid], r1 = rs[wid + 1];
      float acc[8] = {0.f, 0.f, 0.f, 0.f, 0.f, 0.f, 0.f, 0.f};
      for (int k = r0; k < r1; k += 8) {
        int kk = k + g;
        int2 c = csr[kk];  // group-uniform address (8 lanes share)
        bool ok = kk < r1;
        float vj = ok ? __int_as_float(c.y) : 0.f;
        int lab = ok ? (int)(((unsigned)c.x) >> 16) : 0;
        float4 raw = *(const float4*)&slab[lab * SLABSTRIDE + li * 8];
        __half2* hp = (__half2*)&raw;
#pragma unroll
        for (int q = 0; q < 4; ++q) {
          float2 f = __half22float2(hp[q]);
          acc[2 * q] = fmaf(f.x, vj, acc[2 * q]);
          acc[2 * q + 1] = fmaf(f.y, vj, acc[2 * q + 1]);
        }
      }
      // reduce the 8 groups (butterfly over lanes 8,16,32)
#pragma unroll
      for (int d = 8; d < 64; d <<= 1) {
#pragma unroll
        for (int q = 0; q < 8; ++q) acc[q] += __shfl_xor(acc[q], d, 64);
      }
      if (lane < 8) {
        float di = dinv[wid];
        int lab0 = labels[wid];
        float4 sraw = *(const float4*)&slab[lab0 * SLABSTRIDE + lane * 8];
        __half2* sp = (__half2*)&sraw;
        float4 bA = *(const float4*)(b1 + p * 64 + lane * 8);
        float4 bB = *(const float4*)(b1 + p * 64 + lane * 8 + 4);
        float bb[8] = {bA.x, bA.y, bA.z, bA.w, bB.x, bB.y, bB.z, bB.w};
        float o[8];
#pragma unroll
        for (int q = 0; q < 4; ++q) {
          float2 sf = __half22float2(sp[q]);
          o[2 * q] = fmaxf(fmaf(acc[2 * q] + sf.x * di, di, bb[2 * q]), 0.f);
          o[2 * q + 1] =
              fmaxf(fmaf(acc[2 * q + 1] + sf.y * di, di, bb[2 * q + 1]), 0.f);
        }
        union { float4 f4; __half2 h2[4]; } u;
#pragma unroll
        for (int q = 0; q < 4; ++q)
          u.h2[q] = __float22half2_rn(make_float2(o[2 * q], o[2 * q + 1]));
        *(float4*)(out1 + (size_t)wid * 128 + p * 64 + lane * 8) = u.f4;
      }
    }
  }
}

// unpack 4 halves (loaded as float2, 8B) -> two float2
__device__ __forceinline__ void unpack4(float2 raw, float2& a, float2& b) {
  union { float f; __half2 h; } u0, u1;
  u0.f = raw.x;
  u1.f = raw.y;
  a = __half22float2(u0.h);
  b = __half22float2(u1.h);
}

// Layer 2 aggregation: out = A_hat h (fp16 gather source, f32 output).
// Pair-gather; csr.y prescaled (no dinv gather).
__global__ __launch_bounds__(256) void agg2_kernel(
    const int* __restrict__ rs, const int2* __restrict__ csr,
    const float* __restrict__ dinv, const __half* __restrict__ h,
    float* __restrict__ out, int n) {
  int wid = (blockIdx.x * blockDim.x + threadIdx.x) >> 6;
  int lane = threadIdx.x & 63;
  if (wid >= n) return;
  int half = lane >> 5, fl = lane & 31;
  float di = dinv[wid];
  float acc0, acc1, acc2, acc3;
  {
    float2 raw = ((const float2*)(h + (size_t)wid * 128))[fl];
    float2 a, b;
    unpack4(raw, a, b);
    float ss = half ? 0.f : di;
    acc0 = a.x * ss; acc1 = a.y * ss; acc2 = b.x * ss; acc3 = b.y * ss;
  }
  int r1v = rs[wid + 1];
  for (int base = rs[wid]; base < r1v; base += 64) {
    int s = 0;
    float v = 0.f;
    if (base + lane < r1v) {
      int2 c = csr[base + lane];
      s = c.x;
      v = __int_as_float(c.y);
    }
    int nb = min(64, r1v - base);
    int j = 0;
    for (; j + 16 <= nb; j += 16) {
#pragma unroll
      for (int u = 0; u < 8; ++u) {
        int jj = j + 2 * u + half;
        int sj = __shfl(s, jj, 64);
        float vj = __shfl(v, jj, 64);
        float2 raw = ((const float2*)(h + (size_t)(sj & 0xffff) * 128))[fl];
        float2 a, b;
        unpack4(raw, a, b);
        acc0 = fmaf(a.x, vj, acc0); acc1 = fmaf(a.y, vj, acc1);
        acc2 = fmaf(b.x, vj, acc2); acc3 = fmaf(b.y, vj, acc3);
      }
    }
    for (; j + 2 <= nb; j += 2) {
      int jj = j + half;
      int sj = __shfl(s, jj, 64);
      float vj = __shfl(v, jj, 64);
      float2 raw = ((const float2*)(h + (size_t)(sj & 0xffff) * 128))[fl];
      float2 a, b;
      unpack4(raw, a, b);
      acc0 = fmaf(a.x, vj, acc0); acc1 = fmaf(a.y, vj, acc1);
      acc2 = fmaf(b.x, vj, acc2); acc3 = fmaf(b.y, vj, acc3);
    }
    if (j < nb) {
      int sj = __shfl(s, j, 64);
      float vj0 = __shfl(v, j, 64);
      float vj = half ? 0.f : vj0;
      float2 raw = ((const float2*)(h + (size_t)(sj & 0xffff) * 128))[fl];
      float2 a, b;
      unpack4(raw, a, b);
      acc0 = fmaf(a.x, vj, acc0); acc1 = fmaf(a.y, vj, acc1);
      acc2 = fmaf(b.x, vj, acc2); acc3 = fmaf(b.y, vj, acc3);
    }
  }
  acc0 += __shfl_xor(acc0, 32, 64);
  acc1 += __shfl_xor(acc1, 32, 64);
  acc2 += __shfl_xor(acc2, 32, 64);
  acc3 += __shfl_xor(acc3, 32, 64);
  if (half == 0) {
    ((float4*)(out + (size_t)wid * 128))[fl] =
        make_float4(acc0 * di, acc1 * di, acc2 * di, acc3 * di);
  }
}

// In-place: y[rb..rb+31] = y[rb..rb+31] @ W + b.
__global__ __launch_bounds__(256) void gemm_bias_kernel(float* __restrict__ y,
                                                        const float* __restrict__ W,
                                                        const float* __restrict__ bias,
                                                        int n) {
  __shared__ float xs[32][128];
  int tid = threadIdx.x;
  int tc = tid & 31;
  int tr = tid >> 5;
  int rb = blockIdx.x * 32;
  {
    const float4* xg = (const float4*)(y + (size_t)rb * 128);
    float4* xls = (float4*)&xs[0][0];
#pragma unroll
    for (int i = 0; i < 4; ++i) {
      int idx = tid + i * 256;
      int row = rb + (idx >> 5);
      float4 val = (row < n) ? xg[idx] : make_float4(0.f, 0.f, 0.f, 0.f);
      xls[idx] = val;
    }
  }
  __syncthreads();
  int j0 = tc * 4;
  float4 b4 = *(const float4*)(bias + j0);
  float acc[4][4];
#pragma unroll
  for (int r = 0; r < 4; ++r) {
    acc[r][0] = b4.x; acc[r][1] = b4.y; acc[r][2] = b4.z; acc[r][3] = b4.w;
  }
#pragma unroll 4
  for (int k = 0; k < 128; ++k) {
    float4 w4 = *(const float4*)(W + k * 128 + j0);
#pragma unroll
    for (int r = 0; r < 4; ++r) {
      float xv = xs[tr * 4 + r][k];
      acc[r][0] = fmaf(xv, w4.x, acc[r][0]);
      acc[r][1] = fmaf(xv, w4.y, acc[r][1]);
      acc[r][2] = fmaf(xv, w4.z, acc[r][2]);
      acc[r][3] = fmaf(xv, w4.w, acc[r][3]);
    }
  }
#pragma unroll
  for (int r = 0; r < 4; ++r) {
    int row = rb + tr * 4 + r;
    if (row < n)
      *(float4*)(y + (size_t)row * 128 + j0) =
          make_float4(acc[r][0], acc[r][1], acc[r][2], acc[r][3]);
  }
}

extern "C" void kernel_launch(void* const* d_in, const int* in_sizes, int n_in,
                              void* d_out, int out_size, void* d_ws, size_t ws_size,
                              hipStream_t stream) {
  const int* labels = (const int*)d_in[0];
  const int* edge_index = (const int*)d_in[1];
  const float* weight = (const float*)d_in[2];
  const float* emb = (const float*)d_in[3];
  const float* W1 = (const float*)d_in[4];
  const float* b1 = (const float*)d_in[5];
  const float* W2 = (const float*)d_in[6];
  const float* b2 = (const float*)d_in[7];

  int n = in_sizes[0];
  int e = in_sizes[1] / 2;
  int vocab = in_sizes[3] / 128;
  const int* srcp = edge_index;
  const int* dstp = edge_index + e;

  int nb = (n + 63) >> 6;                 // dst buckets (782)
  int chunk = (e + CHUNKS - 1) / CHUNKS;  // 6250
  int bact = (e + chunk - 1) / chunk;

  float* ws = (float*)d_ws;
  size_t o = 0;
  auto alloc_f = [&](size_t c) { float* p = ws + o; o += (c + 255) & ~(size_t)255; return p; };
  int*    hist  = (int*)alloc_f((size_t)nb * CHUNKS);
  int*    off   = (int*)alloc_f((size_t)nb * CHUNKS);
  int*    tot   = (int*)alloc_f(nb);
  int*    ebase = (int*)alloc_f(nb + 1);
  int2*   brec  = (int2*)alloc_f((size_t)e * 2);
  int*    rs    = (int*)alloc_f(n + 1);
  int2*   csr   = (int2*)alloc_f((size_t)e * 2 + 16);  // +8 records slack
  float*  dinv  = alloc_f(n);
  __half* temb2 = (__half*)alloc_f((size_t)vocab * 64);  // [2][vocab][64] halves
  __half* out1  = (__half*)alloc_f((size_t)n * 64);      // n*128 halves
  (void)ws_size;

  dim3 b256(256);
  dim3 b1024(1024);
  int gagg = (int)(((size_t)n * 64 + 255) / 256);

  hist_kernel<<<bact, b1024, 0, stream>>>(dstp, hist, e, chunk, nb);
  colscan_kernel<<<(nb * 64 + 255) / 256, b256, 0, stream>>>(hist, off, tot, nb, bact);
  ebase_kernel<<<1, b1024, 0, stream>>>(tot, ebase, nb);
  scatter_kernel<<<bact, b1024, 0, stream>>>(srcp, dstp, weight, labels, off, ebase,
                                             brec, e, chunk, nb);
  bsort_kernel<<<nb, b256, 0, stream>>>(brec, ebase, csr, rs, dinv, n);
  scale_kernel<<<(e + 255) / 256, b256, 0, stream>>>(csr, dinv, e);
  temb_kernel<<<vocab, 128, 0, stream>>>(emb, W1, temb2, vocab);
  // layer 1: out1 = relu(A_hat temb[labels] + b1)  (LDS slab, 2 passes)
  agg1_kernel<<<256, 512, 0, stream>>>(rs, csr, dinv, labels, temb2, b1, out1, n,
                                       vocab);
  // layer 2: d_out = (A_hat out1) @ W2 + b2
  agg2_kernel<<<gagg, b256, 0, stream>>>(rs, csr, dinv, out1, (float*)d_out, n);
  gemm_bias_kernel<<<(n + 31) / 32, b256, 0, stream>>>((float*)d_out, W2, b2, n);
}

// Round 12
// 183.325 us; speedup vs baseline: 1.3672x; 1.3672x over previous
//
#include <hip/hip_runtime.h>
#include <hip/hip_fp16.h>

// ---------------------------------------------------------------------------
// 2-layer GCN on MI355X.
//   GCNConv(x) = A_hat (x W) + b = (A_hat x) W + b, and emb[labels]@W1 =
//   (emb@W1)[labels] -> layer 1 gathers from a 256KB fp16 L2-resident table;
//   layer 2 aggregates first, then in-place GEMM on d_out.
// CSR build (zero global atomics): K1 hist (+fused temb) / K2 colscan /
// K2b ebase / K3 scatter / K4 bsort (+dinv fold).
// Aggs: R8/R10 pair-gather (proven): batch-64 edge records coalesced,
// shfl-broadcast pairs, 2x32 lanes x 4 feats (8B half4 gathers), dinv[src]
// applied per-lane in the batch phase; NEXT-BATCH PREFETCH hoists the csr
// record+dinv load of batch k+1 above batch k's broadcast loop (removes
// csr->shfl->gather serial latency on multi-batch rows).
// R11 lesson (LDS-slab agg1, 111us): 141KB LDS -> 1 block/CU kills latency
// hiding; ds_read_b128 at random rows bank-conflicts (2.4M). Register
// pair-gather + high occupancy is the right agg1 structure.
// ---------------------------------------------------------------------------

#define CHUNKS 256  // chunk = ceil(e/256) = 6250 for e=1.6M
#define BSTAGE 2816 // bucket stage entries (avg bucket = 2048)

// K1: blocks [0,bact): per-chunk histogram of dst-buckets.
//     blocks [bact, bact+ceil(vocab/8)): temb = emb @ W1 (8 rows/block, fp16).
__global__ __launch_bounds__(1024) void hist_temb_kernel(
    const int* __restrict__ dst, int* __restrict__ hist, int e, int chunk,
    int nb, int bact, const float* __restrict__ emb,
    const float* __restrict__ W1, __half* __restrict__ temb, int vocab) {
  __shared__ unsigned lh[1024];
  __shared__ float xs[8][128];
  int b = blockIdx.x, t = threadIdx.x;
  if (b < bact) {
    lh[t] = 0;
    __syncthreads();
    int start = b * chunk, end = min(e, start + chunk);
    for (int i = start + t; i < end; i += 1024) atomicAdd(&lh[dst[i] >> 6], 1u);
    __syncthreads();
    if (t < nb) hist[(size_t)t * CHUNKS + b] = (int)lh[t];
  } else {
    int r = (b - bact) * 8 + (t >> 7);
    int j = t & 127;
    if (r < vocab) xs[t >> 7][j] = emb[r * 128 + j];
    __syncthreads();
    if (r < vocab) {
      float acc = 0.f;
#pragma unroll 8
      for (int k = 0; k < 128; ++k) acc = fmaf(xs[t >> 7][k], W1[k * 128 + j], acc);
      temb[r * 128 + j] = __float2half_rn(acc);
    }
  }
}

// K2: one wave per bucket k: exclusive scan of hist[k][*] over chunks.
__global__ __launch_bounds__(256) void colscan_kernel(const int* __restrict__ hist,
                                                      int* __restrict__ off,
                                                      int* __restrict__ tot,
                                                      int nb, int bact) {
  int k = (blockIdx.x * 256 + threadIdx.x) >> 6;
  int lane = threadIdx.x & 63;
  if (k >= nb) return;
  int carry = 0;
  for (int r = 0; r < CHUNKS / 64; ++r) {
    int b = r * 64 + lane;
    int h = (b < bact) ? hist[(size_t)k * CHUNKS + b] : 0;
    int x = h;
#pragma unroll
    for (int d = 1; d < 64; d <<= 1) {
      int tt = __shfl_up(x, d, 64);
      if (lane >= d) x += tt;
    }
    if (b < bact) off[(size_t)k * CHUNKS + b] = carry + x - h;
    carry += __shfl(x, 63, 64);
  }
  if (lane == 0) tot[k] = carry;
}

// K2b: single block: exclusive scan of tot[nb] -> ebase[nb+1].
__global__ __launch_bounds__(1024) void ebase_kernel(const int* __restrict__ tot,
                                                     int* __restrict__ ebase, int nb) {
  __shared__ int wsum[16];
  int t = threadIdx.x, lane = t & 63, wv = t >> 6;
  int v = (t < nb) ? tot[t] : 0;
  int x = v;
#pragma unroll
  for (int d = 1; d < 64; d <<= 1) {
    int tt = __shfl_up(x, d, 64);
    if (lane >= d) x += tt;
  }
  if (lane == 63) wsum[wv] = x;
  __syncthreads();
  int o = 0;
#pragma unroll
  for (int w = 0; w < 16; ++w) o += (w < wv) ? wsum[w] : 0;
  int excl = x - v + o;
  if (t < nb) ebase[t] = excl;
  if (t == nb - 1) ebase[nb] = excl + v;
}

// K3: scatter edges into bucket-grouped records (LDS rank, no global atomics).
__global__ __launch_bounds__(1024) void scatter_kernel(
    const int* __restrict__ src, const int* __restrict__ dst,
    const float* __restrict__ w, const int* __restrict__ labels,
    const int* __restrict__ off, const int* __restrict__ ebase,
    int2* __restrict__ brec, int e, int chunk, int nb) {
  __shared__ unsigned bincnt[1024];
  __shared__ int gbase[1024];
  int b = blockIdx.x, t = threadIdx.x;
  bincnt[t] = 0;
  if (t < nb) gbase[t] = ebase[t] + off[(size_t)t * CHUNKS + b];
  __syncthreads();
  int start = b * chunk, end = min(e, start + chunk);
  int s[7], d[7], lb[7], ps[7];
  float wv[7];
#pragma unroll
  for (int u = 0; u < 7; ++u) {
    int i = start + u * 1024 + t;
    bool ok = i < end;
    s[u] = ok ? src[i] : 0;
    d[u] = ok ? dst[i] : 0;
    wv[u] = ok ? w[i] : 0.f;
  }
#pragma unroll
  for (int u = 0; u < 7; ++u) lb[u] = labels[s[u]];
#pragma unroll
  for (int u = 0; u < 7; ++u) ps[u] = gbase[d[u] >> 6];
#pragma unroll
  for (int u = 0; u < 7; ++u) {
    int i = start + u * 1024 + t;
    if (i < end) {
      int k = d[u] >> 6;
      unsigned lr = atomicAdd(&bincnt[k], 1u);
      unsigned rx = (unsigned)s[u] | ((unsigned)(d[u] & 63) << 16) |
                    ((unsigned)lb[u] << 22);
      brec[ps[u] + (int)lr] = make_int2((int)rx, __float_as_int(wv[u]));
    }
  }
}

// K4: per-bucket 64-bin sort: brec -> csr (src|label<<16, w), + rs[] + dinv.
__global__ __launch_bounds__(256) void bsort_kernel(const int2* __restrict__ brec,
                                                    const int* __restrict__ ebase,
                                                    int2* __restrict__ csr,
                                                    int* __restrict__ rs,
                                                    float* __restrict__ dinv, int n) {
  __shared__ int2 stage[BSTAGE];
  __shared__ unsigned h64[64];
  __shared__ unsigned cur[64];
  __shared__ float rsum[64];
  int k = blockIdx.x, t = threadIdx.x;
  int e0 = ebase[k], e1 = ebase[k + 1], cnt = e1 - e0;
  if (t < 64) { h64[t] = 0; rsum[t] = 0.f; }
  __syncthreads();
  bool fits = (cnt <= BSTAGE);
  for (int i = t; i < cnt; i += 256) {
    int2 r = brec[e0 + i];
    if (fits) stage[i] = r;
    unsigned dl = ((unsigned)r.x >> 16) & 63u;
    atomicAdd(&h64[dl], 1u);
    atomicAdd(&rsum[dl], __int_as_float(r.y));
  }
  __syncthreads();
  if (t < 64) {
    int hv = (int)h64[t];
    int x = hv;
#pragma unroll
    for (int d = 1; d < 64; d <<= 1) {
      int tt = __shfl_up(x, d, 64);
      if (t >= d) x += tt;
    }
    int ex = x - hv;
    cur[t] = (unsigned)(e0 + ex);
    int v = k * 64 + t;
    if (v <= n) rs[v] = e0 + ex;
    if (v < n) dinv[v] = rsqrtf(1.0f + rsum[t]);
  }
  __syncthreads();
  for (int i = t; i < cnt; i += 256) {
    int2 r = fits ? stage[i] : brec[e0 + i];
    unsigned rx = (unsigned)r.x;
    int dl = (int)((rx >> 16) & 63u);
    int pos = (int)atomicAdd(&cur[dl], 1u);
    csr[pos] = make_int2((int)((rx & 0xffffu) | ((rx >> 22) << 16)), r.y);
  }
}

// unpack 4 halves (loaded as float2, 8B) -> two float2
__device__ __forceinline__ void unpack4(float2 raw, float2& a, float2& b) {
  union { float f; __half2 h; } u0, u1;
  u0.f = raw.x;
  u1.f = raw.y;
  a = __half22float2(u0.h);
  b = __half22float2(u1.h);
}

// Layer 1: out1 = relu(A_hat temb[labels] + b1), fp16 in/out. Pair-gather
// with next-batch prefetch. Lane owns features 4*fl..4*fl+3 (half=lane>>5
// handles edges j+half).
__global__ __launch_bounds__(256) void agg1_kernel(
    const int* __restrict__ rs, const int2* __restrict__ csr,
    const float* __restrict__ dinv, const int* __restrict__ labels,
    const __half* __restrict__ temb, const float* __restrict__ b1,
    __half* __restrict__ out1, int n) {
  int wid = (blockIdx.x * blockDim.x + threadIdx.x) >> 6;
  int lane = threadIdx.x & 63;
  if (wid >= n) return;
  int half = lane >> 5, fl = lane & 31;
  float di = dinv[wid];
  float acc0, acc1, acc2, acc3;
  {
    int selfrow = labels[wid];
    float2 raw = ((const float2*)(temb + (size_t)selfrow * 128))[fl];
    float2 a, b;
    unpack4(raw, a, b);
    float ss = half ? 0.f : di;  // self term once (half 0 only)
    acc0 = a.x * ss; acc1 = a.y * ss; acc2 = b.x * ss; acc3 = b.y * ss;
  }
  int base0 = rs[wid], r1v = rs[wid + 1];
  int s = 0;
  float v = 0.f;
  if (base0 + lane < r1v) {
    int2 c = csr[base0 + lane];
    s = c.x;
    v = __int_as_float(c.y) * dinv[c.x & 0xffff];
  }
  for (int base = base0; base < r1v; base += 64) {
    // prefetch next batch before the broadcast loop
    int ns = 0;
    float nv = 0.f;
    if (base + 64 + lane < r1v) {
      int2 c = csr[base + 64 + lane];
      ns = c.x;
      nv = __int_as_float(c.y) * dinv[c.x & 0xffff];
    }
    int nb = min(64, r1v - base);
    int j = 0;
    for (; j + 16 <= nb; j += 16) {
#pragma unroll
      for (int u = 0; u < 8; ++u) {
        int jj = j + 2 * u + half;
        int sj = __shfl(s, jj, 64);
        float vj = __shfl(v, jj, 64);
        float2 raw = ((const float2*)(temb + (size_t)(sj >> 16) * 128))[fl];
        float2 a, b;
        unpack4(raw, a, b);
        acc0 = fmaf(a.x, vj, acc0); acc1 = fmaf(a.y, vj, acc1);
        acc2 = fmaf(b.x, vj, acc2); acc3 = fmaf(b.y, vj, acc3);
      }
    }
    for (; j + 2 <= nb; j += 2) {
      int jj = j + half;
      int sj = __shfl(s, jj, 64);
      float vj = __shfl(v, jj, 64);
      float2 raw = ((const float2*)(temb + (size_t)(sj >> 16) * 128))[fl];
      float2 a, b;
      unpack4(raw, a, b);
      acc0 = fmaf(a.x, vj, acc0); acc1 = fmaf(a.y, vj, acc1);
      acc2 = fmaf(b.x, vj, acc2); acc3 = fmaf(b.y, vj, acc3);
    }
    if (j < nb) {  // leftover single edge: half 1 contributes 0
      int sj = __shfl(s, j, 64);
      float vj0 = __shfl(v, j, 64);
      float vj = half ? 0.f : vj0;
      float2 raw = ((const float2*)(temb + (size_t)(sj >> 16) * 128))[fl];
      float2 a, b;
      unpack4(raw, a, b);
      acc0 = fmaf(a.x, vj, acc0); acc1 = fmaf(a.y, vj, acc1);
      acc2 = fmaf(b.x, vj, acc2); acc3 = fmaf(b.y, vj, acc3);
    }
    s = ns;
    v = nv;
  }
  acc0 += __shfl_xor(acc0, 32, 64);
  acc1 += __shfl_xor(acc1, 32, 64);
  acc2 += __shfl_xor(acc2, 32, 64);
  acc3 += __shfl_xor(acc3, 32, 64);
  if (half == 0) {
    float4 b4 = ((const float4*)b1)[fl];
    acc0 = fmaxf(fmaf(acc0, di, b4.x), 0.f);
    acc1 = fmaxf(fmaf(acc1, di, b4.y), 0.f);
    acc2 = fmaxf(fmaf(acc2, di, b4.z), 0.f);
    acc3 = fmaxf(fmaf(acc3, di, b4.w), 0.f);
    union { float2 f2; __half2 h2[2]; } o;
    o.h2[0] = __float22half2_rn(make_float2(acc0, acc1));
    o.h2[1] = __float22half2_rn(make_float2(acc2, acc3));
    ((float2*)(out1 + (size_t)wid * 128))[fl] = o.f2;
  }
}

// Layer 2 aggregation: out = A_hat h (fp16 gather source, f32 output).
// Pair-gather with next-batch prefetch.
__global__ __launch_bounds__(256) void agg2_kernel(
    const int* __restrict__ rs, const int2* __restrict__ csr,
    const float* __restrict__ dinv, const __half* __restrict__ h,
    float* __restrict__ out, int n) {
  int wid = (blockIdx.x * blockDim.x + threadIdx.x) >> 6;
  int lane = threadIdx.x & 63;
  if (wid >= n) return;
  int half = lane >> 5, fl = lane & 31;
  float di = dinv[wid];
  float acc0, acc1, acc2, acc3;
  {
    float2 raw = ((const float2*)(h + (size_t)wid * 128))[fl];
    float2 a, b;
    unpack4(raw, a, b);
    float ss = half ? 0.f : di;
    acc0 = a.x * ss; acc1 = a.y * ss; acc2 = b.x * ss; acc3 = b.y * ss;
  }
  int base0 = rs[wid], r1v = rs[wid + 1];
  int s = 0;
  float v = 0.f;
  if (base0 + lane < r1v) {
    int2 c = csr[base0 + lane];
    s = c.x;
    v = __int_as_float(c.y) * dinv[c.x & 0xffff];
  }
  for (int base = base0; base < r1v; base += 64) {
    int ns = 0;
    float nv = 0.f;
    if (base + 64 + lane < r1v) {
      int2 c = csr[base + 64 + lane];
      ns = c.x;
      nv = __int_as_float(c.y) * dinv[c.x & 0xffff];
    }
    int nb = min(64, r1v - base);
    int j = 0;
    for (; j + 16 <= nb; j += 16) {
#pragma unroll
      for (int u = 0; u < 8; ++u) {
        int jj = j + 2 * u + half;
        int sj = __shfl(s, jj, 64);
        float vj = __shfl(v, jj, 64);
        float2 raw = ((const float2*)(h + (size_t)(sj & 0xffff) * 128))[fl];
        float2 a, b;
        unpack4(raw, a, b);
        acc0 = fmaf(a.x, vj, acc0); acc1 = fmaf(a.y, vj, acc1);
        acc2 = fmaf(b.x, vj, acc2); acc3 = fmaf(b.y, vj, acc3);
      }
    }
    for (; j + 2 <= nb; j += 2) {
      int jj = j + half;
      int sj = __shfl(s, jj, 64);
      float vj = __shfl(v, jj, 64);
      float2 raw = ((const float2*)(h + (size_t)(sj & 0xffff) * 128))[fl];
      float2 a, b;
      unpack4(raw, a, b);
      acc0 = fmaf(a.x, vj, acc0); acc1 = fmaf(a.y, vj, acc1);
      acc2 = fmaf(b.x, vj, acc2); acc3 = fmaf(b.y, vj, acc3);
    }
    if (j < nb) {
      int sj = __shfl(s, j, 64);
      float vj0 = __shfl(v, j, 64);
      float vj = half ? 0.f : vj0;
      float2 raw = ((const float2*)(h + (size_t)(sj & 0xffff) * 128))[fl];
      float2 a, b;
      unpack4(raw, a, b);
      acc0 = fmaf(a.x, vj, acc0); acc1 = fmaf(a.y, vj, acc1);
      acc2 = fmaf(b.x, vj, acc2); acc3 = fmaf(b.y, vj, acc3);
    }
    s = ns;
    v = nv;
  }
  acc0 += __shfl_xor(acc0, 32, 64);
  acc1 += __shfl_xor(acc1, 32, 64);
  acc2 += __shfl_xor(acc2, 32, 64);
  acc3 += __shfl_xor(acc3, 32, 64);
  if (half == 0) {
    ((float4*)(out + (size_t)wid * 128))[fl] =
        make_float4(acc0 * di, acc1 * di, acc2 * di, acc3 * di);
  }
}

// In-place: y[rb..rb+31] = y[rb..rb+31] @ W + b.
__global__ __launch_bounds__(256) void gemm_bias_kernel(float* __restrict__ y,
                                                        const float* __restrict__ W,
                                                        const float* __restrict__ bias,
                                                        int n) {
  __shared__ float xs[32][128];
  int tid = threadIdx.x;
  int tc = tid & 31;
  int tr = tid >> 5;
  int rb = blockIdx.x * 32;
  {
    const float4* xg = (const float4*)(y + (size_t)rb * 128);
    float4* xls = (float4*)&xs[0][0];
#pragma unroll
    for (int i = 0; i < 4; ++i) {
      int idx = tid + i * 256;
      int row = rb + (idx >> 5);
      float4 val = (row < n) ? xg[idx] : make_float4(0.f, 0.f, 0.f, 0.f);
      xls[idx] = val;
    }
  }
  __syncthreads();
  int j0 = tc * 4;
  float4 b4 = *(const float4*)(bias + j0);
  float acc[4][4];
#pragma unroll
  for (int r = 0; r < 4; ++r) {
    acc[r][0] = b4.x; acc[r][1] = b4.y; acc[r][2] = b4.z; acc[r][3] = b4.w;
  }
#pragma unroll 4
  for (int k = 0; k < 128; ++k) {
    float4 w4 = *(const float4*)(W + k * 128 + j0);
#pragma unroll
    for (int r = 0; r < 4; ++r) {
      float xv = xs[tr * 4 + r][k];
      acc[r][0] = fmaf(xv, w4.x, acc[r][0]);
      acc[r][1] = fmaf(xv, w4.y, acc[r][1]);
      acc[r][2] = fmaf(xv, w4.z, acc[r][2]);
      acc[r][3] = fmaf(xv, w4.w, acc[r][3]);
    }
  }
#pragma unroll
  for (int r = 0; r < 4; ++r) {
    int row = rb + tr * 4 + r;
    if (row < n)
      *(float4*)(y + (size_t)row * 128 + j0) =
          make_float4(acc[r][0], acc[r][1], acc[r][2], acc[r][3]);
  }
}

extern "C" void kernel_launch(void* const* d_in, const int* in_sizes, int n_in,
                              void* d_out, int out_size, void* d_ws, size_t ws_size,
                              hipStream_t stream) {
  const int* labels = (const int*)d_in[0];
  const int* edge_index = (const int*)d_in[1];
  const float* weight = (const float*)d_in[2];
  const float* emb = (const float*)d_in[3];
  const float* W1 = (const float*)d_in[4];
  const float* b1 = (const float*)d_in[5];
  const float* W2 = (const float*)d_in[6];
  const float* b2 = (const float*)d_in[7];

  int n = in_sizes[0];
  int e = in_sizes[1] / 2;
  int vocab = in_sizes[3] / 128;
  const int* srcp = edge_index;
  const int* dstp = edge_index + e;

  int nb = (n + 63) >> 6;                 // dst buckets (782)
  int chunk = (e + CHUNKS - 1) / CHUNKS;  // 6250
  int bact = (e + chunk - 1) / chunk;
  int tblocks = (vocab + 7) / 8;          // temb blocks (125)

  float* ws = (float*)d_ws;
  size_t o = 0;
  auto alloc_f = [&](size_t c) { float* p = ws + o; o += (c + 255) & ~(size_t)255; return p; };
  int*    hist  = (int*)alloc_f((size_t)nb * CHUNKS);
  int*    off   = (int*)alloc_f((size_t)nb * CHUNKS);
  int*    tot   = (int*)alloc_f(nb);
  int*    ebase = (int*)alloc_f(nb + 1);
  int2*   brec  = (int2*)alloc_f((size_t)e * 2);
  int*    rs    = (int*)alloc_f(n + 1);
  int2*   csr   = (int2*)alloc_f((size_t)e * 2);
  float*  dinv  = alloc_f(n);
  __half* temb  = (__half*)alloc_f((size_t)vocab * 64);  // vocab*128 halves
  __half* out1  = (__half*)alloc_f((size_t)n * 64);      // n*128 halves
  (void)ws_size;

  dim3 b256(256);
  dim3 b1024(1024);
  int gagg = (int)(((size_t)n * 64 + 255) / 256);

  hist_temb_kernel<<<bact + tblocks, b1024, 0, stream>>>(dstp, hist, e, chunk, nb,
                                                         bact, emb, W1, temb, vocab);
  colscan_kernel<<<(nb * 64 + 255) / 256, b256, 0, stream>>>(hist, off, tot, nb, bact);
  ebase_kernel<<<1, b1024, 0, stream>>>(tot, ebase, nb);
  scatter_kernel<<<bact, b1024, 0, stream>>>(srcp, dstp, weight, labels, off, ebase,
                                             brec, e, chunk, nb);
  bsort_kernel<<<nb, b256, 0, stream>>>(brec, ebase, csr, rs, dinv, n);
  // layer 1: out1 = relu(A_hat temb[labels] + b1)  (fp16 in/out)
  agg1_kernel<<<gagg, b256, 0, stream>>>(rs, csr, dinv, labels, temb, b1, out1, n);
  // layer 2: d_out = (A_hat out1) @ W2 + b2   (agg first, then in-place GEMM)
  agg2_kernel<<<gagg, b256, 0, stream>>>(rs, csr, dinv, out1, (float*)d_out, n);
  gemm_bias_kernel<<<(n + 31) / 32, b256, 0, stream>>>((float*)d_out, W2, b2, n);
}

// Round 13
// 180.595 us; speedup vs baseline: 1.3879x; 1.0151x over previous
//
#include <hip/hip_runtime.h>
#include <hip/hip_fp16.h>

// ---------------------------------------------------------------------------
// 2-layer GCN on MI355X.
//   GCNConv(x) = A_hat (x W) + b = (A_hat x) W + b, and emb[labels]@W1 =
//   (emb@W1)[labels] -> layer 1 gathers from a 256KB fp16 L2-resident table;
//   layer 2 aggregates first, then in-place GEMM on d_out.
// CSR build (zero global atomics): K1 hist (+fused temb) / K2 colscan /
// K2b ebase / K3 scatter / K4 bsort (+dinv fold, 2-way split histograms and
// cursors to halve LDS same-address atomic serialization).
// Aggs: pair-gather (proven R8/R10/R12): batch-64 edge records coalesced,
// shfl-broadcast pairs, 2x32 lanes x 4 feats (8B half4 gathers), dinv[src]
// applied per-lane in the batch phase, next-batch prefetch. Gathers use
// uniform-base + 32-bit byte offsets (saddr form, fewer VALU addr ops).
// R11 lesson: LDS-slab agg1 (1 block/CU, bank conflicts) is 2.4x worse than
// register pair-gather + high occupancy. R9 lesson: aggs are at an
// issue/latency floor, not cache-bound -- L2-resident agg1 ~= L3 agg2.
// ---------------------------------------------------------------------------

#define CHUNKS 256  // chunk = ceil(e/256) = 6250 for e=1.6M
#define BSTAGE 2816 // bucket stage entries (avg bucket = 2048)

// K1: blocks [0,bact): per-chunk histogram of dst-buckets.
//     blocks [bact, bact+ceil(vocab/8)): temb = emb @ W1 (8 rows/block, fp16).
__global__ __launch_bounds__(1024) void hist_temb_kernel(
    const int* __restrict__ dst, int* __restrict__ hist, int e, int chunk,
    int nb, int bact, const float* __restrict__ emb,
    const float* __restrict__ W1, __half* __restrict__ temb, int vocab) {
  __shared__ unsigned lh[1024];
  __shared__ float xs[8][128];
  int b = blockIdx.x, t = threadIdx.x;
  if (b < bact) {
    lh[t] = 0;
    __syncthreads();
    int start = b * chunk, end = min(e, start + chunk);
    for (int i = start + t; i < end; i += 1024) atomicAdd(&lh[dst[i] >> 6], 1u);
    __syncthreads();
    if (t < nb) hist[(size_t)t * CHUNKS + b] = (int)lh[t];
  } else {
    int r = (b - bact) * 8 + (t >> 7);
    int j = t & 127;
    if (r < vocab) xs[t >> 7][j] = emb[r * 128 + j];
    __syncthreads();
    if (r < vocab) {
      float acc = 0.f;
#pragma unroll 8
      for (int k = 0; k < 128; ++k) acc = fmaf(xs[t >> 7][k], W1[k * 128 + j], acc);
      temb[r * 128 + j] = __float2half_rn(acc);
    }
  }
}

// K2: one wave per bucket k: exclusive scan of hist[k][*] over chunks.
__global__ __launch_bounds__(256) void colscan_kernel(const int* __restrict__ hist,
                                                      int* __restrict__ off,
                                                      int* __restrict__ tot,
                                                      int nb, int bact) {
  int k = (blockIdx.x * 256 + threadIdx.x) >> 6;
  int lane = threadIdx.x & 63;
  if (k >= nb) return;
  int carry = 0;
  for (int r = 0; r < CHUNKS / 64; ++r) {
    int b = r * 64 + lane;
    int h = (b < bact) ? hist[(size_t)k * CHUNKS + b] : 0;
    int x = h;
#pragma unroll
    for (int d = 1; d < 64; d <<= 1) {
      int tt = __shfl_up(x, d, 64);
      if (lane >= d) x += tt;
    }
    if (b < bact) off[(size_t)k * CHUNKS + b] = carry + x - h;
    carry += __shfl(x, 63, 64);
  }
  if (lane == 0) tot[k] = carry;
}

// K2b: single block: exclusive scan of tot[nb] -> ebase[nb+1].
__global__ __launch_bounds__(1024) void ebase_kernel(const int* __restrict__ tot,
                                                     int* __restrict__ ebase, int nb) {
  __shared__ int wsum[16];
  int t = threadIdx.x, lane = t & 63, wv = t >> 6;
  int v = (t < nb) ? tot[t] : 0;
  int x = v;
#pragma unroll
  for (int d = 1; d < 64; d <<= 1) {
    int tt = __shfl_up(x, d, 64);
    if (lane >= d) x += tt;
  }
  if (lane == 63) wsum[wv] = x;
  __syncthreads();
  int o = 0;
#pragma unroll
  for (int w = 0; w < 16; ++w) o += (w < wv) ? wsum[w] : 0;
  int excl = x - v + o;
  if (t < nb) ebase[t] = excl;
  if (t == nb - 1) ebase[nb] = excl + v;
}

// K3: scatter edges into bucket-grouped records (LDS rank, no global atomics).
__global__ __launch_bounds__(1024) void scatter_kernel(
    const int* __restrict__ src, const int* __restrict__ dst,
    const float* __restrict__ w, const int* __restrict__ labels,
    const int* __restrict__ off, const int* __restrict__ ebase,
    int2* __restrict__ brec, int e, int chunk, int nb) {
  __shared__ unsigned bincnt[1024];
  __shared__ int gbase[1024];
  int b = blockIdx.x, t = threadIdx.x;
  bincnt[t] = 0;
  if (t < nb) gbase[t] = ebase[t] + off[(size_t)t * CHUNKS + b];
  __syncthreads();
  int start = b * chunk, end = min(e, start + chunk);
  int s[7], d[7], lb[7], ps[7];
  float wv[7];
#pragma unroll
  for (int u = 0; u < 7; ++u) {
    int i = start + u * 1024 + t;
    bool ok = i < end;
    s[u] = ok ? src[i] : 0;
    d[u] = ok ? dst[i] : 0;
    wv[u] = ok ? w[i] : 0.f;
  }
#pragma unroll
  for (int u = 0; u < 7; ++u) lb[u] = labels[s[u]];
#pragma unroll
  for (int u = 0; u < 7; ++u) ps[u] = gbase[d[u] >> 6];
#pragma unroll
  for (int u = 0; u < 7; ++u) {
    int i = start + u * 1024 + t;
    if (i < end) {
      int k = d[u] >> 6;
      unsigned lr = atomicAdd(&bincnt[k], 1u);
      unsigned rx = (unsigned)s[u] | ((unsigned)(d[u] & 63) << 16) |
                    ((unsigned)lb[u] << 22);
      brec[ps[u] + (int)lr] = make_int2((int)rx, __float_as_int(wv[u]));
    }
  }
}

// K4: per-bucket 64-bin sort: brec -> csr (src|label<<16, w), + rs[] + dinv.
// 2-way split histograms/cursors (p = t>>7) halve same-address LDS atomic
// serialization; thread t keeps the same p in both passes so positions are
// unique and deterministic.
__global__ __launch_bounds__(256) void bsort_kernel(const int2* __restrict__ brec,
                                                    const int* __restrict__ ebase,
                                                    int2* __restrict__ csr,
                                                    int* __restrict__ rs,
                                                    float* __restrict__ dinv, int n) {
  __shared__ int2 stage[BSTAGE];
  __shared__ unsigned h64[2][64];
  __shared__ unsigned cur[2][64];
  __shared__ float rsum[2][64];
  int k = blockIdx.x, t = threadIdx.x;
  int p = t >> 7;
  int e0 = ebase[k], e1 = ebase[k + 1], cnt = e1 - e0;
  if (t < 128) { h64[t >> 6][t & 63] = 0; rsum[t >> 6][t & 63] = 0.f; }
  __syncthreads();
  bool fits = (cnt <= BSTAGE);
  for (int i = t; i < cnt; i += 256) {
    int2 r = brec[e0 + i];
    if (fits) stage[i] = r;
    unsigned dl = ((unsigned)r.x >> 16) & 63u;
    atomicAdd(&h64[p][dl], 1u);
    atomicAdd(&rsum[p][dl], __int_as_float(r.y));
  }
  __syncthreads();
  if (t < 64) {
    int h0 = (int)h64[0][t];
    int hv = h0 + (int)h64[1][t];
    int x = hv;
#pragma unroll
    for (int d = 1; d < 64; d <<= 1) {
      int tt = __shfl_up(x, d, 64);
      if (t >= d) x += tt;
    }
    int ex = x - hv;
    cur[0][t] = (unsigned)(e0 + ex);
    cur[1][t] = (unsigned)(e0 + ex + h0);
    int v = k * 64 + t;
    if (v <= n) rs[v] = e0 + ex;
    if (v < n) dinv[v] = rsqrtf(1.0f + rsum[0][t] + rsum[1][t]);
  }
  __syncthreads();
  for (int i = t; i < cnt; i += 256) {
    int2 r = fits ? stage[i] : brec[e0 + i];
    unsigned rx = (unsigned)r.x;
    int dl = (int)((rx >> 16) & 63u);
    int pos = (int)atomicAdd(&cur[p][dl], 1u);
    csr[pos] = make_int2((int)((rx & 0xffffu) | ((rx >> 22) << 16)), r.y);
  }
}

// unpack 4 halves (loaded as float2, 8B) -> two float2
__device__ __forceinline__ void unpack4(float2 raw, float2& a, float2& b) {
  union { float f; __half2 h; } u0, u1;
  u0.f = raw.x;
  u1.f = raw.y;
  a = __half22float2(u0.h);
  b = __half22float2(u1.h);
}

// Layer 1: out1 = relu(A_hat temb[labels] + b1), fp16 in/out. Pair-gather
// with next-batch prefetch; 32-bit byte-offset gathers (saddr form).
__global__ __launch_bounds__(256) void agg1_kernel(
    const int* __restrict__ rs, const int2* __restrict__ csr,
    const float* __restrict__ dinv, const int* __restrict__ labels,
    const __half* __restrict__ temb, const float* __restrict__ b1,
    __half* __restrict__ out1, int n) {
  int wid = (blockIdx.x * blockDim.x + threadIdx.x) >> 6;
  int lane = threadIdx.x & 63;
  if (wid >= n) return;
  int half = lane >> 5, fl = lane & 31;
  unsigned flo = (unsigned)(fl << 3);
  const char* tb = (const char*)temb;
  float di = dinv[wid];
  float acc0, acc1, acc2, acc3;
  {
    unsigned off = ((unsigned)labels[wid] << 8) + flo;
    float2 raw = *(const float2*)(tb + off);
    float2 a, b;
    unpack4(raw, a, b);
    float ss = half ? 0.f : di;  // self term once (half 0 only)
    acc0 = a.x * ss; acc1 = a.y * ss; acc2 = b.x * ss; acc3 = b.y * ss;
  }
  int base0 = rs[wid], r1v = rs[wid + 1];
  int s = 0;
  float v = 0.f;
  if (base0 + lane < r1v) {
    int2 c = csr[base0 + lane];
    s = c.x;
    v = __int_as_float(c.y) * dinv[c.x & 0xffff];
  }
  for (int base = base0; base < r1v; base += 64) {
    int ns = 0;
    float nv = 0.f;
    if (base + 64 + lane < r1v) {
      int2 c = csr[base + 64 + lane];
      ns = c.x;
      nv = __int_as_float(c.y) * dinv[c.x & 0xffff];
    }
    int nb = min(64, r1v - base);
    int j = 0;
    for (; j + 16 <= nb; j += 16) {
#pragma unroll
      for (int u = 0; u < 8; ++u) {
        int jj = j + 2 * u + half;
        int sj = __shfl(s, jj, 64);
        float vj = __shfl(v, jj, 64);
        unsigned off = (((unsigned)sj >> 16) << 8) + flo;
        float2 raw = *(const float2*)(tb + off);
        float2 a, b;
        unpack4(raw, a, b);
        acc0 = fmaf(a.x, vj, acc0); acc1 = fmaf(a.y, vj, acc1);
        acc2 = fmaf(b.x, vj, acc2); acc3 = fmaf(b.y, vj, acc3);
      }
    }
    for (; j + 2 <= nb; j += 2) {
      int jj = j + half;
      int sj = __shfl(s, jj, 64);
      float vj = __shfl(v, jj, 64);
      unsigned off = (((unsigned)sj >> 16) << 8) + flo;
      float2 raw = *(const float2*)(tb + off);
      float2 a, b;
      unpack4(raw, a, b);
      acc0 = fmaf(a.x, vj, acc0); acc1 = fmaf(a.y, vj, acc1);
      acc2 = fmaf(b.x, vj, acc2); acc3 = fmaf(b.y, vj, acc3);
    }
    if (j < nb) {  // leftover single edge: half 1 contributes 0
      int sj = __shfl(s, j, 64);
      float vj0 = __shfl(v, j, 64);
      float vj = half ? 0.f : vj0;
      unsigned off = (((unsigned)sj >> 16) << 8) + flo;
      float2 raw = *(const float2*)(tb + off);
      float2 a, b;
      unpack4(raw, a, b);
      acc0 = fmaf(a.x, vj, acc0); acc1 = fmaf(a.y, vj, acc1);
      acc2 = fmaf(b.x, vj, acc2); acc3 = fmaf(b.y, vj, acc3);
    }
    s = ns;
    v = nv;
  }
  acc0 += __shfl_xor(acc0, 32, 64);
  acc1 += __shfl_xor(acc1, 32, 64);
  acc2 += __shfl_xor(acc2, 32, 64);
  acc3 += __shfl_xor(acc3, 32, 64);
  if (half == 0) {
    float4 b4 = ((const float4*)b1)[fl];
    acc0 = fmaxf(fmaf(acc0, di, b4.x), 0.f);
    acc1 = fmaxf(fmaf(acc1, di, b4.y), 0.f);
    acc2 = fmaxf(fmaf(acc2, di, b4.z), 0.f);
    acc3 = fmaxf(fmaf(acc3, di, b4.w), 0.f);
    union { float2 f2; __half2 h2[2]; } o;
    o.h2[0] = __float22half2_rn(make_float2(acc0, acc1));
    o.h2[1] = __float22half2_rn(make_float2(acc2, acc3));
    ((float2*)(out1 + (size_t)wid * 128))[fl] = o.f2;
  }
}

// Layer 2 aggregation: out = A_hat h (fp16 gather source, f32 output).
// Pair-gather with next-batch prefetch; 32-bit byte-offset gathers.
__global__ __launch_bounds__(256) void agg2_kernel(
    const int* __restrict__ rs, const int2* __restrict__ csr,
    const float* __restrict__ dinv, const __half* __restrict__ h,
    float* __restrict__ out, int n) {
  int wid = (blockIdx.x * blockDim.x + threadIdx.x) >> 6;
  int lane = threadIdx.x & 63;
  if (wid >= n) return;
  int half = lane >> 5, fl = lane & 31;
  unsigned flo = (unsigned)(fl << 3);
  const char* hb = (const char*)h;
  float di = dinv[wid];
  float acc0, acc1, acc2, acc3;
  {
    float2 raw = *(const float2*)(hb + ((unsigned)wid << 8) + flo);
    float2 a, b;
    unpack4(raw, a, b);
    float ss = half ? 0.f : di;
    acc0 = a.x * ss; acc1 = a.y * ss; acc2 = b.x * ss; acc3 = b.y * ss;
  }
  int base0 = rs[wid], r1v = rs[wid + 1];
  int s = 0;
  float v = 0.f;
  if (base0 + lane < r1v) {
    int2 c = csr[base0 + lane];
    s = c.x;
    v = __int_as_float(c.y) * dinv[c.x & 0xffff];
  }
  for (int base = base0; base < r1v; base += 64) {
    int ns = 0;
    float nv = 0.f;
    if (base + 64 + lane < r1v) {
      int2 c = csr[base + 64 + lane];
      ns = c.x;
      nv = __int_as_float(c.y) * dinv[c.x & 0xffff];
    }
    int nb = min(64, r1v - base);
    int j = 0;
    for (; j + 16 <= nb; j += 16) {
#pragma unroll
      for (int u = 0; u < 8; ++u) {
        int jj = j + 2 * u + half;
        int sj = __shfl(s, jj, 64);
        float vj = __shfl(v, jj, 64);
        unsigned off = (((unsigned)sj & 0xffffu) << 8) + flo;
        float2 raw = *(const float2*)(hb + off);
        float2 a, b;
        unpack4(raw, a, b);
        acc0 = fmaf(a.x, vj, acc0); acc1 = fmaf(a.y, vj, acc1);
        acc2 = fmaf(b.x, vj, acc2); acc3 = fmaf(b.y, vj, acc3);
      }
    }
    for (; j + 2 <= nb; j += 2) {
      int jj = j + half;
      int sj = __shfl(s, jj, 64);
      float vj = __shfl(v, jj, 64);
      unsigned off = (((unsigned)sj & 0xffffu) << 8) + flo;
      float2 raw = *(const float2*)(hb + off);
      float2 a, b;
      unpack4(raw, a, b);
      acc0 = fmaf(a.x, vj, acc0); acc1 = fmaf(a.y, vj, acc1);
      acc2 = fmaf(b.x, vj, acc2); acc3 = fmaf(b.y, vj, acc3);
    }
    if (j < nb) {
      int sj = __shfl(s, j, 64);
      float vj0 = __shfl(v, j, 64);
      float vj = half ? 0.f : vj0;
      unsigned off = (((unsigned)sj & 0xffffu) << 8) + flo;
      float2 raw = *(const float2*)(hb + off);
      float2 a, b;
      unpack4(raw, a, b);
      acc0 = fmaf(a.x, vj, acc0); acc1 = fmaf(a.y, vj, acc1);
      acc2 = fmaf(b.x, vj, acc2); acc3 = fmaf(b.y, vj, acc3);
    }
    s = ns;
    v = nv;
  }
  acc0 += __shfl_xor(acc0, 32, 64);
  acc1 += __shfl_xor(acc1, 32, 64);
  acc2 += __shfl_xor(acc2, 32, 64);
  acc3 += __shfl_xor(acc3, 32, 64);
  if (half == 0) {
    ((float4*)(out + (size_t)wid * 128))[fl] =
        make_float4(acc0 * di, acc1 * di, acc2 * di, acc3 * di);
  }
}

// In-place: y[rb..rb+31] = y[rb..rb+31] @ W + b.
__global__ __launch_bounds__(256) void gemm_bias_kernel(float* __restrict__ y,
                                                        const float* __restrict__ W,
                                                        const float* __restrict__ bias,
                                                        int n) {
  __shared__ float xs[32][128];
  int tid = threadIdx.x;
  int tc = tid & 31;
  int tr = tid >> 5;
  int rb = blockIdx.x * 32;
  {
    const float4* xg = (const float4*)(y + (size_t)rb * 128);
    float4* xls = (float4*)&xs[0][0];
#pragma unroll
    for (int i = 0; i < 4; ++i) {
      int idx = tid + i * 256;
      int row = rb + (idx >> 5);
      float4 val = (row < n) ? xg[idx] : make_float4(0.f, 0.f, 0.f, 0.f);
      xls[idx] = val;
    }
  }
  __syncthreads();
  int j0 = tc * 4;
  float4 b4 = *(const float4*)(bias + j0);
  float acc[4][4];
#pragma unroll
  for (int r = 0; r < 4; ++r) {
    acc[r][0] = b4.x; acc[r][1] = b4.y; acc[r][2] = b4.z; acc[r][3] = b4.w;
  }
#pragma unroll 4
  for (int k = 0; k < 128; ++k) {
    float4 w4 = *(const float4*)(W + k * 128 + j0);
#pragma unroll
    for (int r = 0; r < 4; ++r) {
      float xv = xs[tr * 4 + r][k];
      acc[r][0] = fmaf(xv, w4.x, acc[r][0]);
      acc[r][1] = fmaf(xv, w4.y, acc[r][1]);
      acc[r][2] = fmaf(xv, w4.z, acc[r][2]);
      acc[r][3] = fmaf(xv, w4.w, acc[r][3]);
    }
  }
#pragma unroll
  for (int r = 0; r < 4; ++r) {
    int row = rb + tr * 4 + r;
    if (row < n)
      *(float4*)(y + (size_t)row * 128 + j0) =
          make_float4(acc[r][0], acc[r][1], acc[r][2], acc[r][3]);
  }
}

extern "C" void kernel_launch(void* const* d_in, const int* in_sizes, int n_in,
                              void* d_out, int out_size, void* d_ws, size_t ws_size,
                              hipStream_t stream) {
  const int* labels = (const int*)d_in[0];
  const int* edge_index = (const int*)d_in[1];
  const float* weight = (const float*)d_in[2];
  const float* emb = (const float*)d_in[3];
  const float* W1 = (const float*)d_in[4];
  const float* b1 = (const float*)d_in[5];
  const float* W2 = (const float*)d_in[6];
  const float* b2 = (const float*)d_in[7];

  int n = in_sizes[0];
  int e = in_sizes[1] / 2;
  int vocab = in_sizes[3] / 128;
  const int* srcp = edge_index;
  const int* dstp = edge_index + e;

  int nb = (n + 63) >> 6;                 // dst buckets (782)
  int chunk = (e + CHUNKS - 1) / CHUNKS;  // 6250
  int bact = (e + chunk - 1) / chunk;
  int tblocks = (vocab + 7) / 8;          // temb blocks (125)

  float* ws = (float*)d_ws;
  size_t o = 0;
  auto alloc_f = [&](size_t c) { float* p = ws + o; o += (c + 255) & ~(size_t)255; return p; };
  int*    hist  = (int*)alloc_f((size_t)nb * CHUNKS);
  int*    off   = (int*)alloc_f((size_t)nb * CHUNKS);
  int*    tot   = (int*)alloc_f(nb);
  int*    ebase = (int*)alloc_f(nb + 1);
  int2*   brec  = (int2*)alloc_f((size_t)e * 2);
  int*    rs    = (int*)alloc_f(n + 1);
  int2*   csr   = (int2*)alloc_f((size_t)e * 2);
  float*  dinv  = alloc_f(n);
  __half* temb  = (__half*)alloc_f((size_t)vocab * 64);  // vocab*128 halves
  __half* out1  = (__half*)alloc_f((size_t)n * 64);      // n*128 halves
  (void)ws_size;

  dim3 b256(256);
  dim3 b1024(1024);
  int gagg = (int)(((size_t)n * 64 + 255) / 256);

  hist_temb_kernel<<<bact + tblocks, b1024, 0, stream>>>(dstp, hist, e, chunk, nb,
                                                         bact, emb, W1, temb, vocab);
  colscan_kernel<<<(nb * 64 + 255) / 256, b256, 0, stream>>>(hist, off, tot, nb, bact);
  ebase_kernel<<<1, b1024, 0, stream>>>(tot, ebase, nb);
  scatter_kernel<<<bact, b1024, 0, stream>>>(srcp, dstp, weight, labels, off, ebase,
                                             brec, e, chunk, nb);
  bsort_kernel<<<nb, b256, 0, stream>>>(brec, ebase, csr, rs, dinv, n);
  // layer 1: out1 = relu(A_hat temb[labels] + b1)  (fp16 in/out)
  agg1_kernel<<<gagg, b256, 0, stream>>>(rs, csr, dinv, labels, temb, b1, out1, n);
  // layer 2: d_out = (A_hat out1) @ W2 + b2   (agg first, then in-place GEMM)
  agg2_kernel<<<gagg, b256, 0, stream>>>(rs, csr, dinv, out1, (float*)d_out, n);
  gemm_bias_kernel<<<(n + 31) / 32, b256, 0, stream>>>((float*)d_out, W2, b2, n);
}

// Round 14
// 165.696 us; speedup vs baseline: 1.5127x; 1.0899x over previous
//
#include <hip/hip_runtime.h>
#include <hip/hip_fp16.h>

// ---------------------------------------------------------------------------
// 2-layer GCN on MI355X.
//   GCNConv(x) = A_hat (x W) + b = (A_hat x) W + b, and emb[labels]@W1 =
//   (emb@W1)[labels] -> layer 1 gathers from a 256KB fp16 L2-resident table;
//   layer 2 aggregates first, then in-place GEMM on d_out.
// CSR build (zero global atomics): K1 hist (+fused temb) / K2 colscan /
// K2b ebase / K3 scatter / K4 bsort (+dinv fold, 2-way split histograms).
// Aggs: pair-gather, batch-64 edge records, shfl-broadcast pairs, next-batch
// prefetch, 32-bit byte-offset gathers.
// R14: out1 stored as FP8 E4M3 (x64 pre-scale; decode via v_cvt_pk_f32_fp8):
// agg2's gather rows shrink 256B->128B, working set 12.8->6.4MB -- agg2 is
// beyond-L2 random-fabric bound (160MB misses @3.5TB/s = its 45us floor),
// so halving bytes + raising L2 hit rate is the only remaining lever.
// ---------------------------------------------------------------------------

#define CHUNKS 256  // chunk = ceil(e/256) = 6250 for e=1.6M
#define BSTAGE 2816 // bucket stage entries (avg bucket = 2048)

typedef float floatx2 __attribute__((ext_vector_type(2)));

// K1: blocks [0,bact): per-chunk histogram of dst-buckets.
//     blocks [bact, bact+ceil(vocab/8)): temb = emb @ W1 (8 rows/block, fp16).
__global__ __launch_bounds__(1024) void hist_temb_kernel(
    const int* __restrict__ dst, int* __restrict__ hist, int e, int chunk,
    int nb, int bact, const float* __restrict__ emb,
    const float* __restrict__ W1, __half* __restrict__ temb, int vocab) {
  __shared__ unsigned lh[1024];
  __shared__ float xs[8][128];
  int b = blockIdx.x, t = threadIdx.x;
  if (b < bact) {
    lh[t] = 0;
    __syncthreads();
    int start = b * chunk, end = min(e, start + chunk);
    for (int i = start + t; i < end; i += 1024) atomicAdd(&lh[dst[i] >> 6], 1u);
    __syncthreads();
    if (t < nb) hist[(size_t)t * CHUNKS + b] = (int)lh[t];
  } else {
    int r = (b - bact) * 8 + (t >> 7);
    int j = t & 127;
    if (r < vocab) xs[t >> 7][j] = emb[r * 128 + j];
    __syncthreads();
    if (r < vocab) {
      float acc = 0.f;
#pragma unroll 8
      for (int k = 0; k < 128; ++k) acc = fmaf(xs[t >> 7][k], W1[k * 128 + j], acc);
      temb[r * 128 + j] = __float2half_rn(acc);
    }
  }
}

// K2: one wave per bucket k: exclusive scan of hist[k][*] over chunks.
__global__ __launch_bounds__(256) void colscan_kernel(const int* __restrict__ hist,
                                                      int* __restrict__ off,
                                                      int* __restrict__ tot,
                                                      int nb, int bact) {
  int k = (blockIdx.x * 256 + threadIdx.x) >> 6;
  int lane = threadIdx.x & 63;
  if (k >= nb) return;
  int carry = 0;
  for (int r = 0; r < CHUNKS / 64; ++r) {
    int b = r * 64 + lane;
    int h = (b < bact) ? hist[(size_t)k * CHUNKS + b] : 0;
    int x = h;
#pragma unroll
    for (int d = 1; d < 64; d <<= 1) {
      int tt = __shfl_up(x, d, 64);
      if (lane >= d) x += tt;
    }
    if (b < bact) off[(size_t)k * CHUNKS + b] = carry + x - h;
    carry += __shfl(x, 63, 64);
  }
  if (lane == 0) tot[k] = carry;
}

// K2b: single block: exclusive scan of tot[nb] -> ebase[nb+1].
__global__ __launch_bounds__(1024) void ebase_kernel(const int* __restrict__ tot,
                                                     int* __restrict__ ebase, int nb) {
  __shared__ int wsum[16];
  int t = threadIdx.x, lane = t & 63, wv = t >> 6;
  int v = (t < nb) ? tot[t] : 0;
  int x = v;
#pragma unroll
  for (int d = 1; d < 64; d <<= 1) {
    int tt = __shfl_up(x, d, 64);
    if (lane >= d) x += tt;
  }
  if (lane == 63) wsum[wv] = x;
  __syncthreads();
  int o = 0;
#pragma unroll
  for (int w = 0; w < 16; ++w) o += (w < wv) ? wsum[w] : 0;
  int excl = x - v + o;
  if (t < nb) ebase[t] = excl;
  if (t == nb - 1) ebase[nb] = excl + v;
}

// K3: scatter edges into bucket-grouped records (LDS rank, no global atomics).
__global__ __launch_bounds__(1024) void scatter_kernel(
    const int* __restrict__ src, const int* __restrict__ dst,
    const float* __restrict__ w, const int* __restrict__ labels,
    const int* __restrict__ off, const int* __restrict__ ebase,
    int2* __restrict__ brec, int e, int chunk, int nb) {
  __shared__ unsigned bincnt[1024];
  __shared__ int gbase[1024];
  int b = blockIdx.x, t = threadIdx.x;
  bincnt[t] = 0;
  if (t < nb) gbase[t] = ebase[t] + off[(size_t)t * CHUNKS + b];
  __syncthreads();
  int start = b * chunk, end = min(e, start + chunk);
  int s[7], d[7], lb[7], ps[7];
  float wv[7];
#pragma unroll
  for (int u = 0; u < 7; ++u) {
    int i = start + u * 1024 + t;
    bool ok = i < end;
    s[u] = ok ? src[i] : 0;
    d[u] = ok ? dst[i] : 0;
    wv[u] = ok ? w[i] : 0.f;
  }
#pragma unroll
  for (int u = 0; u < 7; ++u) lb[u] = labels[s[u]];
#pragma unroll
  for (int u = 0; u < 7; ++u) ps[u] = gbase[d[u] >> 6];
#pragma unroll
  for (int u = 0; u < 7; ++u) {
    int i = start + u * 1024 + t;
    if (i < end) {
      int k = d[u] >> 6;
      unsigned lr = atomicAdd(&bincnt[k], 1u);
      unsigned rx = (unsigned)s[u] | ((unsigned)(d[u] & 63) << 16) |
                    ((unsigned)lb[u] << 22);
      brec[ps[u] + (int)lr] = make_int2((int)rx, __float_as_int(wv[u]));
    }
  }
}

// K4: per-bucket 64-bin sort: brec -> csr (src|label<<16, w), + rs[] + dinv.
// 2-way split histograms/cursors halve same-address LDS atomic serialization.
__global__ __launch_bounds__(256) void bsort_kernel(const int2* __restrict__ brec,
                                                    const int* __restrict__ ebase,
                                                    int2* __restrict__ csr,
                                                    int* __restrict__ rs,
                                                    float* __restrict__ dinv, int n) {
  __shared__ int2 stage[BSTAGE];
  __shared__ unsigned h64[2][64];
  __shared__ unsigned cur[2][64];
  __shared__ float rsum[2][64];
  int k = blockIdx.x, t = threadIdx.x;
  int p = t >> 7;
  int e0 = ebase[k], e1 = ebase[k + 1], cnt = e1 - e0;
  if (t < 128) { h64[t >> 6][t & 63] = 0; rsum[t >> 6][t & 63] = 0.f; }
  __syncthreads();
  bool fits = (cnt <= BSTAGE);
  for (int i = t; i < cnt; i += 256) {
    int2 r = brec[e0 + i];
    if (fits) stage[i] = r;
    unsigned dl = ((unsigned)r.x >> 16) & 63u;
    atomicAdd(&h64[p][dl], 1u);
    atomicAdd(&rsum[p][dl], __int_as_float(r.y));
  }
  __syncthreads();
  if (t < 64) {
    int h0 = (int)h64[0][t];
    int hv = h0 + (int)h64[1][t];
    int x = hv;
#pragma unroll
    for (int d = 1; d < 64; d <<= 1) {
      int tt = __shfl_up(x, d, 64);
      if (t >= d) x += tt;
    }
    int ex = x - hv;
    cur[0][t] = (unsigned)(e0 + ex);
    cur[1][t] = (unsigned)(e0 + ex + h0);
    int v = k * 64 + t;
    if (v <= n) rs[v] = e0 + ex;
    if (v < n) dinv[v] = rsqrtf(1.0f + rsum[0][t] + rsum[1][t]);
  }
  __syncthreads();
  for (int i = t; i < cnt; i += 256) {
    int2 r = fits ? stage[i] : brec[e0 + i];
    unsigned rx = (unsigned)r.x;
    int dl = (int)((rx >> 16) & 63u);
    int pos = (int)atomicAdd(&cur[p][dl], 1u);
    csr[pos] = make_int2((int)((rx & 0xffffu) | ((rx >> 22) << 16)), r.y);
  }
}

// unpack 4 halves (loaded as float2, 8B) -> two float2
__device__ __forceinline__ void unpack4(float2 raw, float2& a, float2& b) {
  union { float f; __half2 h; } u0, u1;
  u0.f = raw.x;
  u1.f = raw.y;
  a = __half22float2(u0.h);
  b = __half22float2(u1.h);
}

// Layer 1: out1 = relu(A_hat temb[labels] + b1), fp16 gathers in, FP8 E4M3
// out (x64 pre-scale). Pair-gather with next-batch prefetch.
__global__ __launch_bounds__(256) void agg1_kernel(
    const int* __restrict__ rs, const int2* __restrict__ csr,
    const float* __restrict__ dinv, const int* __restrict__ labels,
    const __half* __restrict__ temb, const float* __restrict__ b1,
    unsigned* __restrict__ out8, int n) {
  int wid = (blockIdx.x * blockDim.x + threadIdx.x) >> 6;
  int lane = threadIdx.x & 63;
  if (wid >= n) return;
  int half = lane >> 5, fl = lane & 31;
  unsigned flo = (unsigned)(fl << 3);
  const char* tb = (const char*)temb;
  float di = dinv[wid];
  float acc0, acc1, acc2, acc3;
  {
    unsigned off = ((unsigned)labels[wid] << 8) + flo;
    float2 raw = *(const float2*)(tb + off);
    float2 a, b;
    unpack4(raw, a, b);
    float ss = half ? 0.f : di;  // self term once (half 0 only)
    acc0 = a.x * ss; acc1 = a.y * ss; acc2 = b.x * ss; acc3 = b.y * ss;
  }
  int base0 = rs[wid], r1v = rs[wid + 1];
  int s = 0;
  float v = 0.f;
  if (base0 + lane < r1v) {
    int2 c = csr[base0 + lane];
    s = c.x;
    v = __int_as_float(c.y) * dinv[c.x & 0xffff];
  }
  for (int base = base0; base < r1v; base += 64) {
    int ns = 0;
    float nv = 0.f;
    if (base + 64 + lane < r1v) {
      int2 c = csr[base + 64 + lane];
      ns = c.x;
      nv = __int_as_float(c.y) * dinv[c.x & 0xffff];
    }
    int nb = min(64, r1v - base);
    int j = 0;
    for (; j + 16 <= nb; j += 16) {
#pragma unroll
      for (int u = 0; u < 8; ++u) {
        int jj = j + 2 * u + half;
        int sj = __shfl(s, jj, 64);
        float vj = __shfl(v, jj, 64);
        unsigned off = (((unsigned)sj >> 16) << 8) + flo;
        float2 raw = *(const float2*)(tb + off);
        float2 a, b;
        unpack4(raw, a, b);
        acc0 = fmaf(a.x, vj, acc0); acc1 = fmaf(a.y, vj, acc1);
        acc2 = fmaf(b.x, vj, acc2); acc3 = fmaf(b.y, vj, acc3);
      }
    }
    for (; j + 2 <= nb; j += 2) {
      int jj = j + half;
      int sj = __shfl(s, jj, 64);
      float vj = __shfl(v, jj, 64);
      unsigned off = (((unsigned)sj >> 16) << 8) + flo;
      float2 raw = *(const float2*)(tb + off);
      float2 a, b;
      unpack4(raw, a, b);
      acc0 = fmaf(a.x, vj, acc0); acc1 = fmaf(a.y, vj, acc1);
      acc2 = fmaf(b.x, vj, acc2); acc3 = fmaf(b.y, vj, acc3);
    }
    if (j < nb) {  // leftover single edge: half 1 contributes 0
      int sj = __shfl(s, j, 64);
      float vj0 = __shfl(v, j, 64);
      float vj = half ? 0.f : vj0;
      unsigned off = (((unsigned)sj >> 16) << 8) + flo;
      float2 raw = *(const float2*)(tb + off);
      float2 a, b;
      unpack4(raw, a, b);
      acc0 = fmaf(a.x, vj, acc0); acc1 = fmaf(a.y, vj, acc1);
      acc2 = fmaf(b.x, vj, acc2); acc3 = fmaf(b.y, vj, acc3);
    }
    s = ns;
    v = nv;
  }
  acc0 += __shfl_xor(acc0, 32, 64);
  acc1 += __shfl_xor(acc1, 32, 64);
  acc2 += __shfl_xor(acc2, 32, 64);
  acc3 += __shfl_xor(acc3, 32, 64);
  if (half == 0) {
    float4 b4 = ((const float4*)b1)[fl];
    acc0 = fmaxf(fmaf(acc0, di, b4.x), 0.f) * 64.f;
    acc1 = fmaxf(fmaf(acc1, di, b4.y), 0.f) * 64.f;
    acc2 = fmaxf(fmaf(acc2, di, b4.z), 0.f) * 64.f;
    acc3 = fmaxf(fmaf(acc3, di, b4.w), 0.f) * 64.f;
    int pk = __builtin_amdgcn_cvt_pk_fp8_f32(acc0, acc1, 0, false);
    pk = __builtin_amdgcn_cvt_pk_fp8_f32(acc2, acc3, pk, true);
    out8[(size_t)wid * 32 + fl] = (unsigned)pk;
  }
}

// Layer 2 aggregation: out = A_hat h (FP8 gather source, f32 output).
// Rows are 128B (32 lanes x 4B). Decode via v_cvt_pk_f32_fp8; final /64.
__global__ __launch_bounds__(256) void agg2_kernel(
    const int* __restrict__ rs, const int2* __restrict__ csr,
    const float* __restrict__ dinv, const unsigned* __restrict__ h8,
    float* __restrict__ out, int n) {
  int wid = (blockIdx.x * blockDim.x + threadIdx.x) >> 6;
  int lane = threadIdx.x & 63;
  if (wid >= n) return;
  int half = lane >> 5, fl = lane & 31;
  unsigned flo = (unsigned)(fl << 2);
  const char* hb = (const char*)h8;
  float di = dinv[wid];
  float acc0, acc1, acc2, acc3;
  {
    unsigned r8 = *(const unsigned*)(hb + ((unsigned)wid << 7) + flo);
    floatx2 a = __builtin_amdgcn_cvt_pk_f32_fp8((int)r8, false);
    floatx2 b = __builtin_amdgcn_cvt_pk_f32_fp8((int)r8, true);
    float ss = half ? 0.f : di;
    acc0 = a[0] * ss; acc1 = a[1] * ss; acc2 = b[0] * ss; acc3 = b[1] * ss;
  }
  int base0 = rs[wid], r1v = rs[wid + 1];
  int s = 0;
  float v = 0.f;
  if (base0 + lane < r1v) {
    int2 c = csr[base0 + lane];
    s = c.x;
    v = __int_as_float(c.y) * dinv[c.x & 0xffff];
  }
  for (int base = base0; base < r1v; base += 64) {
    int ns = 0;
    float nv = 0.f;
    if (base + 64 + lane < r1v) {
      int2 c = csr[base + 64 + lane];
      ns = c.x;
      nv = __int_as_float(c.y) * dinv[c.x & 0xffff];
    }
    int nb = min(64, r1v - base);
    int j = 0;
    for (; j + 16 <= nb; j += 16) {
#pragma unroll
      for (int u = 0; u < 8; ++u) {
        int jj = j + 2 * u + half;
        int sj = __shfl(s, jj, 64);
        float vj = __shfl(v, jj, 64);
        unsigned off = (((unsigned)sj & 0xffffu) << 7) + flo;
        unsigned r8 = *(const unsigned*)(hb + off);
        floatx2 a = __builtin_amdgcn_cvt_pk_f32_fp8((int)r8, false);
        floatx2 b = __builtin_amdgcn_cvt_pk_f32_fp8((int)r8, true);
        acc0 = fmaf(a[0], vj, acc0); acc1 = fmaf(a[1], vj, acc1);
        acc2 = fmaf(b[0], vj, acc2); acc3 = fmaf(b[1], vj, acc3);
      }
    }
    for (; j + 2 <= nb; j += 2) {
      int jj = j + half;
      int sj = __shfl(s, jj, 64);
      float vj = __shfl(v, jj, 64);
      unsigned off = (((unsigned)sj & 0xffffu) << 7) + flo;
      unsigned r8 = *(const unsigned*)(hb + off);
      floatx2 a = __builtin_amdgcn_cvt_pk_f32_fp8((int)r8, false);
      floatx2 b = __builtin_amdgcn_cvt_pk_f32_fp8((int)r8, true);
      acc0 = fmaf(a[0], vj, acc0); acc1 = fmaf(a[1], vj, acc1);
      acc2 = fmaf(b[0], vj, acc2); acc3 = fmaf(b[1], vj, acc3);
    }
    if (j < nb) {
      int sj = __shfl(s, j, 64);
      float vj0 = __shfl(v, j, 64);
      float vj = half ? 0.f : vj0;
      unsigned off = (((unsigned)sj & 0xffffu) << 7) + flo;
      unsigned r8 = *(const unsigned*)(hb + off);
      floatx2 a = __builtin_amdgcn_cvt_pk_f32_fp8((int)r8, false);
      floatx2 b = __builtin_amdgcn_cvt_pk_f32_fp8((int)r8, true);
      acc0 = fmaf(a[0], vj, acc0); acc1 = fmaf(a[1], vj, acc1);
      acc2 = fmaf(b[0], vj, acc2); acc3 = fmaf(b[1], vj, acc3);
    }
    s = ns;
    v = nv;
  }
  acc0 += __shfl_xor(acc0, 32, 64);
  acc1 += __shfl_xor(acc1, 32, 64);
  acc2 += __shfl_xor(acc2, 32, 64);
  acc3 += __shfl_xor(acc3, 32, 64);
  if (half == 0) {
    float sc = di * 0.015625f;  // /64 de-scale
    ((float4*)(out + (size_t)wid * 128))[fl] =
        make_float4(acc0 * sc, acc1 * sc, acc2 * sc, acc3 * sc);
  }
}

// In-place: y[rb..rb+31] = y[rb..rb+31] @ W + b.
__global__ __launch_bounds__(256) void gemm_bias_kernel(float* __restrict__ y,
                                                        const float* __restrict__ W,
                                                        const float* __restrict__ bias,
                                                        int n) {
  __shared__ float xs[32][128];
  int tid = threadIdx.x;
  int tc = tid & 31;
  int tr = tid >> 5;
  int rb = blockIdx.x * 32;
  {
    const float4* xg = (const float4*)(y + (size_t)rb * 128);
    float4* xls = (float4*)&xs[0][0];
#pragma unroll
    for (int i = 0; i < 4; ++i) {
      int idx = tid + i * 256;
      int row = rb + (idx >> 5);
      float4 val = (row < n) ? xg[idx] : make_float4(0.f, 0.f, 0.f, 0.f);
      xls[idx] = val;
    }
  }
  __syncthreads();
  int j0 = tc * 4;
  float4 b4 = *(const float4*)(bias + j0);
  float acc[4][4];
#pragma unroll
  for (int r = 0; r < 4; ++r) {
    acc[r][0] = b4.x; acc[r][1] = b4.y; acc[r][2] = b4.z; acc[r][3] = b4.w;
  }
#pragma unroll 4
  for (int k = 0; k < 128; ++k) {
    float4 w4 = *(const float4*)(W + k * 128 + j0);
#pragma unroll
    for (int r = 0; r < 4; ++r) {
      float xv = xs[tr * 4 + r][k];
      acc[r][0] = fmaf(xv, w4.x, acc[r][0]);
      acc[r][1] = fmaf(xv, w4.y, acc[r][1]);
      acc[r][2] = fmaf(xv, w4.z, acc[r][2]);
      acc[r][3] = fmaf(xv, w4.w, acc[r][3]);
    }
  }
#pragma unroll
  for (int r = 0; r < 4; ++r) {
    int row = rb + tr * 4 + r;
    if (row < n)
      *(float4*)(y + (size_t)row * 128 + j0) =
          make_float4(acc[r][0], acc[r][1], acc[r][2], acc[r][3]);
  }
}

extern "C" void kernel_launch(void* const* d_in, const int* in_sizes, int n_in,
                              void* d_out, int out_size, void* d_ws, size_t ws_size,
                              hipStream_t stream) {
  const int* labels = (const int*)d_in[0];
  const int* edge_index = (const int*)d_in[1];
  const float* weight = (const float*)d_in[2];
  const float* emb = (const float*)d_in[3];
  const float* W1 = (const float*)d_in[4];
  const float* b1 = (const float*)d_in[5];
  const float* W2 = (const float*)d_in[6];
  const float* b2 = (const float*)d_in[7];

  int n = in_sizes[0];
  int e = in_sizes[1] / 2;
  int vocab = in_sizes[3] / 128;
  const int* srcp = edge_index;
  const int* dstp = edge_index + e;

  int nb = (n + 63) >> 6;                 // dst buckets (782)
  int chunk = (e + CHUNKS - 1) / CHUNKS;  // 6250
  int bact = (e + chunk - 1) / chunk;
  int tblocks = (vocab + 7) / 8;          // temb blocks (125)

  float* ws = (float*)d_ws;
  size_t o = 0;
  auto alloc_f = [&](size_t c) { float* p = ws + o; o += (c + 255) & ~(size_t)255; return p; };
  int*      hist  = (int*)alloc_f((size_t)nb * CHUNKS);
  int*      off   = (int*)alloc_f((size_t)nb * CHUNKS);
  int*      tot   = (int*)alloc_f(nb);
  int*      ebase = (int*)alloc_f(nb + 1);
  int2*     brec  = (int2*)alloc_f((size_t)e * 2);
  int*      rs    = (int*)alloc_f(n + 1);
  int2*     csr   = (int2*)alloc_f((size_t)e * 2);
  float*    dinv  = alloc_f(n);
  __half*   temb  = (__half*)alloc_f((size_t)vocab * 64);  // vocab*128 halves
  unsigned* out8  = (unsigned*)alloc_f((size_t)n * 32);    // n*128 fp8
  (void)ws_size;

  dim3 b256(256);
  dim3 b1024(1024);
  int gagg = (int)(((size_t)n * 64 + 255) / 256);

  hist_temb_kernel<<<bact + tblocks, b1024, 0, stream>>>(dstp, hist, e, chunk, nb,
                                                         bact, emb, W1, temb, vocab);
  colscan_kernel<<<(nb * 64 + 255) / 256, b256, 0, stream>>>(hist, off, tot, nb, bact);
  ebase_kernel<<<1, b1024, 0, stream>>>(tot, ebase, nb);
  scatter_kernel<<<bact, b1024, 0, stream>>>(srcp, dstp, weight, labels, off, ebase,
                                             brec, e, chunk, nb);
  bsort_kernel<<<nb, b256, 0, stream>>>(brec, ebase, csr, rs, dinv, n);
  // layer 1: out8 = fp8(relu(A_hat temb[labels] + b1) * 64)
  agg1_kernel<<<gagg, b256, 0, stream>>>(rs, csr, dinv, labels, temb, b1, out8, n);
  // layer 2: d_out = (A_hat out1) @ W2 + b2   (agg first, then in-place GEMM)
  agg2_kernel<<<gagg, b256, 0, stream>>>(rs, csr, dinv, out8, (float*)d_out, n);
  gemm_bias_kernel<<<(n + 31) / 32, b256, 0, stream>>>((float*)d_out, W2, b2, n);
}